// Round 1
// baseline (177.744 us; speedup 1.0000x reference)
//
#include <hip/hip_runtime.h>
#include <hip/hip_bf16.h>

// Problem constants (fixed by reference)
#define NB     512     // batch N
#define INF    1024    // IN_FEATURES
#define OUTF   64      // OUT_FEATURES
#define KD     16      // KERNEL_DIMS
#define PROJ   (OUTF*KD)   // 1024, GEMM N-dim
#define OROW   (INF + OUTF) // 1088, output row length

// ---------------------------------------------------------------------------
// Kernel 1: M[512][1024] = x[512][1024] @ T[1024][1024]  (fp32, vector ALU)
// Tile 64(M) x 32(N), BK=16, 256 threads, 4x2 micro-tile. 256 blocks = 1/CU.
// ---------------------------------------------------------------------------
#define GBM 64
#define GBN 32
#define GBK 16

__global__ __launch_bounds__(256) void gemm_f32(const float* __restrict__ A,
                                                const float* __restrict__ B,
                                                float* __restrict__ C) {
    __shared__ float As[GBK][GBM + 4];  // +4 keeps rows 16B-aligned, breaks stride
    __shared__ float Bs[GBK][GBN + 4];

    const int t  = threadIdx.x;
    const int bm = blockIdx.y * GBM;
    const int bn = blockIdx.x * GBN;

    // micro-tile coords: 16 m-groups x 16 n-groups
    const int tm = (t >> 4) * 4;   // 0..60
    const int tn = (t & 15) * 2;   // 0..30

    // A-load coords: 64 rows x 16 cols = 1024 floats, one float4 per thread
    const int am = t >> 2;         // 0..63
    const int ak = (t & 3) * 4;    // 0,4,8,12
    // B-load coords: 16 rows x 32 cols = 512 floats, one float2 per thread
    const int bk  = t >> 4;        // 0..15
    const int bn2 = (t & 15) * 2;  // 0..30

    float acc[4][2] = {};

    for (int k0 = 0; k0 < INF; k0 += GBK) {
        const float4 av = *(const float4*)&A[(bm + am) * INF + k0 + ak];
        const float2 bv = *(const float2*)&B[(k0 + bk) * PROJ + bn + bn2];
        __syncthreads();   // protect previous iteration's LDS reads
        As[ak + 0][am] = av.x;
        As[ak + 1][am] = av.y;
        As[ak + 2][am] = av.z;
        As[ak + 3][am] = av.w;
        Bs[bk][bn2]     = bv.x;
        Bs[bk][bn2 + 1] = bv.y;
        __syncthreads();

#pragma unroll
        for (int kk = 0; kk < GBK; ++kk) {
            const float4 a = *(const float4*)&As[kk][tm];
            const float2 b = *(const float2*)&Bs[kk][tn];
            acc[0][0] += a.x * b.x;  acc[0][1] += a.x * b.y;
            acc[1][0] += a.y * b.x;  acc[1][1] += a.y * b.y;
            acc[2][0] += a.z * b.x;  acc[2][1] += a.z * b.y;
            acc[3][0] += a.w * b.x;  acc[3][1] += a.w * b.y;
        }
    }

#pragma unroll
    for (int mi = 0; mi < 4; ++mi) {
        const int row = bm + tm + mi;
        C[row * PROJ + bn + tn]     = acc[mi][0];
        C[row * PROJ + bn + tn + 1] = acc[mi][1];
    }
}

// ---------------------------------------------------------------------------
// Kernel 2: pairwise L1 + exp + masked sum over j.
// Block = 32 i x 4 o (128 threads); grid (16 o-groups, 16 i-groups) = 256 blocks.
// Thread holds its M[i, o, 0..15] in registers; j-rows staged 64 at a time in
// LDS (64 j x 4 o x 16 k = 16 KB). Lanes with the same o broadcast-read.
// Self term (j==i, norm=0 -> exp=1) removed by subtracting 1 at the end.
// ---------------------------------------------------------------------------
__global__ __launch_bounds__(128) void pairwise_l1(const float* __restrict__ M,
                                                   float* __restrict__ out) {
    __shared__ float Mj[64 * 64];  // [j_local][o(4)*16 + k]

    const int t  = threadIdx.x;
    const int o  = t & 3;          // 0..3
    const int il = t >> 2;         // 0..31
    const int og = blockIdx.x;     // 0..15
    const int ig = blockIdx.y;     // 0..15
    const int i  = ig * 32 + il;

    // my row fragment: M[i, og*4+o, 0..15]
    const float4* myp = (const float4*)&M[i * PROJ + og * 64 + o * 16];
    const float4 a0 = myp[0], a1 = myp[1], a2 = myp[2], a3 = myp[3];

    float sum0 = 0.f, sum1 = 0.f;

    for (int j0 = 0; j0 < NB; j0 += 64) {
        __syncthreads();
        // stage 64 rows x 64 floats (this block's 4-o slice), 4096 floats
#pragma unroll
        for (int c = 0; c < 8; ++c) {
            const int idx = (c * 128 + t) * 4;   // float index 0..4092
            const int jl  = idx >> 6;
            const int col = idx & 63;
            *(float4*)&Mj[jl * 64 + col] =
                *(const float4*)&M[(j0 + jl) * PROJ + og * 64 + col];
        }
        __syncthreads();

#pragma unroll 4
        for (int jl = 0; jl < 64; ++jl) {
            const float4* bp = (const float4*)&Mj[jl * 64 + o * 16];
            const float4 b0 = bp[0], b1 = bp[1], b2 = bp[2], b3 = bp[3];
            float n0 = fabsf(a0.x - b0.x) + fabsf(a0.y - b0.y) +
                       fabsf(a0.z - b0.z) + fabsf(a0.w - b0.w);
            float n1 = fabsf(a1.x - b1.x) + fabsf(a1.y - b1.y) +
                       fabsf(a1.z - b1.z) + fabsf(a1.w - b1.w);
            float n2 = fabsf(a2.x - b2.x) + fabsf(a2.y - b2.y) +
                       fabsf(a2.z - b2.z) + fabsf(a2.w - b2.w);
            float n3 = fabsf(a3.x - b3.x) + fabsf(a3.y - b3.y) +
                       fabsf(a3.z - b3.z) + fabsf(a3.w - b3.w);
            const float norm = (n0 + n1) + (n2 + n3);
            if (jl & 1) sum1 += __expf(-norm);
            else        sum0 += __expf(-norm);
        }
    }

    // exclude self-similarity: j==i contributed exp(0)=1
    out[i * OROW + INF + og * 4 + o] = (sum0 + sum1) - 1.0f;
}

// ---------------------------------------------------------------------------
// Kernel 3: copy x into out[:, 0:1024]
// ---------------------------------------------------------------------------
__global__ __launch_bounds__(256) void copy_x(const float* __restrict__ x,
                                              float* __restrict__ out) {
    const int row = blockIdx.x;
    const int c   = threadIdx.x * 4;
    *(float4*)&out[row * OROW + c] = *(const float4*)&x[row * INF + c];
}

extern "C" void kernel_launch(void* const* d_in, const int* in_sizes, int n_in,
                              void* d_out, int out_size, void* d_ws, size_t ws_size,
                              hipStream_t stream) {
    const float* x = (const float*)d_in[0];   // [512,1024] fp32
    const float* T = (const float*)d_in[1];   // [1024,64,16] fp32 (= [1024,1024])
    float* out = (float*)d_out;               // [512,1088] fp32
    float* M   = (float*)d_ws;                // [512,1024] fp32 scratch (2 MB)

    // GEMM: M = x @ T
    gemm_f32<<<dim3(PROJ / GBN, NB / GBM), 256, 0, stream>>>(x, T, M);
    // Pairwise L1 -> exp -> masked row-sum, writes out[:, 1024:1088]
    pairwise_l1<<<dim3(OUTF / 4, NB / 32), 128, 0, stream>>>(M, out);
    // Copy x -> out[:, 0:1024]
    copy_x<<<dim3(NB), 256, 0, stream>>>(x, out);
}

// Round 2
// 101.146 us; speedup vs baseline: 1.7573x; 1.7573x over previous
//
#include <hip/hip_runtime.h>
#include <hip/hip_bf16.h>

// Problem constants (fixed by reference)
#define NB     512
#define INF    1024
#define OUTF   64
#define KD     16
#define PROJ   (OUTF*KD)    // 1024
#define OROW   (INF + OUTF) // 1088

typedef short short8 __attribute__((ext_vector_type(8)));
typedef float floatx4 __attribute__((ext_vector_type(4)));

__device__ __forceinline__ unsigned short f2bf(float f) {
    union { float f; unsigned u; } v; v.f = f;
    const unsigned u = v.u;
    return (unsigned short)((u + 0x7FFF + ((u >> 16) & 1)) >> 16);  // RNE
}

// ---------------------------------------------------------------------------
// Kernel 1: copy x -> out[:,0:1024], init out[:,1024:1088] = -1
// (-1 absorbs the self-similarity term: diagonal contributes exp(0)=1)
// ---------------------------------------------------------------------------
__global__ __launch_bounds__(256) void copy_init(const float* __restrict__ x,
                                                 float* __restrict__ out) {
    const int row = blockIdx.x;
    const int t   = threadIdx.x;
    ((float4*)(out + (size_t)row * OROW))[t] =
        ((const float4*)(x + (size_t)row * INF))[t];
    if (t < 16) {
        ((float4*)(out + (size_t)row * OROW + INF))[t] =
            make_float4(-1.f, -1.f, -1.f, -1.f);
    }
}

// ---------------------------------------------------------------------------
// Kernel 2: M = x @ T via bf16 MFMA (16x16x32), fp32->bf16 on the fly.
// Block: 256 thr (4 waves), tile 32M x 64N, BK=32. Grid (16,16) = 256 blocks.
// Wave w: m-half (w&1)*16, n-half (w>>1)*32 -> two 16x16 acc tiles.
// LDS rows stride 40 shorts (80B = 5*16B): b128 frag reads aligned, 2-way banks.
// ---------------------------------------------------------------------------
#define LDT 40

__global__ __launch_bounds__(256) void gemm_mfma(const float* __restrict__ A,
                                                 const float* __restrict__ B,
                                                 float* __restrict__ C) {
    __shared__ short As[32 * LDT];   // [m][k]
    __shared__ short Bs[64 * LDT];   // [n][k] (transposed on stage)

    const int t    = threadIdx.x;
    const int lane = t & 63, w = t >> 6;
    const int bm = blockIdx.y * 32, bn = blockIdx.x * 64;
    const int mh = w & 1, nh = w >> 1;

    // A staging: 32 rows x 32 k = 1024 floats, 1 float4/thread
    const int am = t >> 3, ak = (t & 7) * 4;
    // B staging: 32 k x 64 n = 2048 floats, 2 float4/thread (rows k, k+1)
    const int bk = (t >> 4) * 2, bn0 = (t & 15) * 4;

    floatx4 acc0 = {0.f, 0.f, 0.f, 0.f};
    floatx4 acc1 = {0.f, 0.f, 0.f, 0.f};

    const int q = lane >> 4, c = lane & 15;
    const short* apf  = &As[(mh * 16 + c) * LDT + q * 8];
    const short* bpf0 = &Bs[(nh * 32 + c) * LDT + q * 8];
    const short* bpf1 = &Bs[(nh * 32 + 16 + c) * LDT + q * 8];

    for (int k0 = 0; k0 < INF; k0 += 32) {
        const float4 av  = *(const float4*)&A[(size_t)(bm + am) * INF + k0 + ak];
        const float4 bv0 = *(const float4*)&B[(size_t)(k0 + bk) * PROJ + bn + bn0];
        const float4 bv1 = *(const float4*)&B[(size_t)(k0 + bk + 1) * PROJ + bn + bn0];

        __syncthreads();   // protect previous iteration's frag reads
        // As[m][ak..ak+3] contiguous: one 8B write
        const unsigned pa0 = f2bf(av.x) | ((unsigned)f2bf(av.y) << 16);
        const unsigned pa1 = f2bf(av.z) | ((unsigned)f2bf(av.w) << 16);
        *(uint2*)&As[am * LDT + ak] = make_uint2(pa0, pa1);
        // Bs[n][bk], Bs[n][bk+1] packed -> 4 b32 writes
        *(unsigned*)&Bs[(bn0 + 0) * LDT + bk] = f2bf(bv0.x) | ((unsigned)f2bf(bv1.x) << 16);
        *(unsigned*)&Bs[(bn0 + 1) * LDT + bk] = f2bf(bv0.y) | ((unsigned)f2bf(bv1.y) << 16);
        *(unsigned*)&Bs[(bn0 + 2) * LDT + bk] = f2bf(bv0.z) | ((unsigned)f2bf(bv1.z) << 16);
        *(unsigned*)&Bs[(bn0 + 3) * LDT + bk] = f2bf(bv0.w) | ((unsigned)f2bf(bv1.w) << 16);
        __syncthreads();

        const short8 af  = *(const short8*)apf;
        const short8 bf0 = *(const short8*)bpf0;
        const short8 bf1 = *(const short8*)bpf1;
        acc0 = __builtin_amdgcn_mfma_f32_16x16x32_bf16(af, bf0, acc0, 0, 0, 0);
        acc1 = __builtin_amdgcn_mfma_f32_16x16x32_bf16(af, bf1, acc1, 0, 0, 0);
    }

    // C/D layout: col = lane&15, row = (lane>>4)*4 + r
#pragma unroll
    for (int r = 0; r < 4; ++r) {
        const int row = bm + mh * 16 + q * 4 + r;
        C[(size_t)row * PROJ + bn + nh * 32 + c]      = acc0[r];
        C[(size_t)row * PROJ + bn + nh * 32 + 16 + c] = acc1[r];
    }
}

// ---------------------------------------------------------------------------
// Kernel 3: pairwise L1 + exp + sum over a 64-row j-slice, atomic accumulate.
// Block = 32 i x 4 o (128 thr); grid (og 16, ig 16, js 8) = 2048 blocks.
// 8 blocks/CU x 16KB LDS = 128KB, 16 waves/CU.
// ---------------------------------------------------------------------------
__global__ __launch_bounds__(128) void pairwise_l1(const float* __restrict__ M,
                                                   float* __restrict__ out) {
    __shared__ float Mj[64 * 64];

    const int t  = threadIdx.x;
    const int o  = t & 3;
    const int il = t >> 2;
    const int og = blockIdx.x;
    const int ig = blockIdx.y;
    const int j0 = blockIdx.z * 64;
    const int i  = ig * 32 + il;

    const float4* myp = (const float4*)&M[(size_t)i * PROJ + og * 64 + o * 16];
    const float4 a0 = myp[0], a1 = myp[1], a2 = myp[2], a3 = myp[3];

    // stage 64 j-rows x 64 floats (this block's 4-o slice)
#pragma unroll
    for (int cc = 0; cc < 8; ++cc) {
        const int idx = (cc * 128 + t) * 4;
        const int jl  = idx >> 6;
        const int col = idx & 63;
        *(float4*)&Mj[jl * 64 + col] =
            *(const float4*)&M[(size_t)(j0 + jl) * PROJ + og * 64 + col];
    }
    __syncthreads();

    float sum0 = 0.f, sum1 = 0.f;
#pragma unroll 4
    for (int jl = 0; jl < 64; ++jl) {
        const float4* bp = (const float4*)&Mj[jl * 64 + o * 16];
        const float4 b0 = bp[0], b1 = bp[1], b2 = bp[2], b3 = bp[3];
        float n0 = fabsf(a0.x - b0.x) + fabsf(a0.y - b0.y) +
                   fabsf(a0.z - b0.z) + fabsf(a0.w - b0.w);
        float n1 = fabsf(a1.x - b1.x) + fabsf(a1.y - b1.y) +
                   fabsf(a1.z - b1.z) + fabsf(a1.w - b1.w);
        float n2 = fabsf(a2.x - b2.x) + fabsf(a2.y - b2.y) +
                   fabsf(a2.z - b2.z) + fabsf(a2.w - b2.w);
        float n3 = fabsf(a3.x - b3.x) + fabsf(a3.y - b3.y) +
                   fabsf(a3.z - b3.z) + fabsf(a3.w - b3.w);
        const float norm = (n0 + n1) + (n2 + n3);
        if (jl & 1) sum1 += __expf(-norm);
        else        sum0 += __expf(-norm);
    }

    __hip_atomic_fetch_add(&out[(size_t)i * OROW + INF + og * 4 + o],
                           sum0 + sum1, __ATOMIC_RELAXED,
                           __HIP_MEMORY_SCOPE_AGENT);
}

extern "C" void kernel_launch(void* const* d_in, const int* in_sizes, int n_in,
                              void* d_out, int out_size, void* d_ws, size_t ws_size,
                              hipStream_t stream) {
    const float* x = (const float*)d_in[0];   // [512,1024] fp32
    const float* T = (const float*)d_in[1];   // [1024,1024] fp32
    float* out = (float*)d_out;               // [512,1088] fp32
    float* M   = (float*)d_ws;                // [512,1024] fp32 scratch

    // init out (-1 in o_b region) BEFORE atomics; copy x while GEMM queue fills
    copy_init<<<dim3(NB), 256, 0, stream>>>(x, out);
    gemm_mfma<<<dim3(PROJ / 64, NB / 32), 256, 0, stream>>>(x, T, M);
    pairwise_l1<<<dim3(OUTF / 4, NB / 32, NB / 64), 128, 0, stream>>>(M, out);
}

// Round 3
// 92.921 us; speedup vs baseline: 1.9128x; 1.0885x over previous
//
#include <hip/hip_runtime.h>
#include <hip/hip_bf16.h>
#include <hip/hip_fp16.h>

// Problem constants (fixed by reference)
#define NB     512
#define INF    1024
#define OUTF   64
#define PROJ   1024          // OUT_FEATURES * KERNEL_DIMS
#define OROW   (INF + OUTF)  // 1088

typedef short short8 __attribute__((ext_vector_type(8)));
typedef float floatx4 __attribute__((ext_vector_type(4)));

#define LDT 40   // LDS row stride in shorts: 80 B = 5*16B -> b128 frags aligned

__device__ __forceinline__ unsigned pack_bf16(float x, float y) {
    __hip_bfloat162 h = __float22bfloat162_rn(make_float2(x, y));  // v_cvt_pk_bf16_f32
    union { __hip_bfloat162 h; unsigned u; } v; v.h = h; return v.u;
}

__device__ __forceinline__ __half2 as_h2(unsigned u) {
    union { unsigned u; __half2 h; } v; v.u = u; return v.h;
}

// ---------------------------------------------------------------------------
// Kernel 1 (fused): M16 = half(x @ T) via bf16 MFMA, + copy x slice -> out,
// + init one o_b row to -1 (absorbs the self-similarity diagonal).
// Tile 16M x 64N, BK=32, 256 thr (4 waves, one 16x16 n-quarter each).
// Grid (16 n, 32 m) = 512 blocks -> 2 blocks/CU, 8 waves/CU.
// Register-prefetch of iter k+1 issued before MFMA(k) hides global latency.
// ---------------------------------------------------------------------------
__global__ __launch_bounds__(256, 2) void gemm_fused(const float* __restrict__ A,
                                                     const float* __restrict__ B,
                                                     float* __restrict__ out,
                                                     __half* __restrict__ M16) {
    __shared__ short As[16 * LDT];
    __shared__ short Bs[64 * LDT];

    const int t    = threadIdx.x;
    const int lane = t & 63, w = t >> 6;
    const int bnx = blockIdx.x, bmy = blockIdx.y;
    const int bm = bmy * 16, bn = bnx * 64;

    // --- fused: copy x[bm..bm+16, bn..bn+64] -> out (16 rows x 64 cols) ---
    {
        const int r = t >> 4, c4 = (t & 15) * 4;
        *(float4*)&out[(size_t)(bm + r) * OROW + bn + c4] =
            *(const float4*)&A[(size_t)(bm + r) * INF + bn + c4];
    }
    // --- fused: out[row, 1024:1088] = -1 for row = linear block id (0..511) ---
    if (t < 16) {
        const int row = bmy * 16 + bnx;
        *(float4*)&out[(size_t)row * OROW + INF + t * 4] =
            make_float4(-1.f, -1.f, -1.f, -1.f);
    }

    // staging coords
    const int am = t >> 4,        ak  = (t & 15) * 2;  // A: 16 rows x 32 k
    const int bk = (t >> 4) * 2,  bn0 = (t & 15) * 4;  // B: 32 k x 64 n

    // fragment pointers: A[m=lane&15][k=(lane>>4)*8+j], B[n][k] likewise
    const int q = lane >> 4, c = lane & 15;
    const short* ap = &As[c * LDT + q * 8];
    const short* bp = &Bs[(w * 16 + c) * LDT + q * 8];

    floatx4 acc = {0.f, 0.f, 0.f, 0.f};

    // prefetch k0 = 0
    float2 av  = *(const float2*)&A[(size_t)(bm + am) * INF + ak];
    float4 bv0 = *(const float4*)&B[(size_t)bk * PROJ + bn + bn0];
    float4 bv1 = *(const float4*)&B[(size_t)(bk + 1) * PROJ + bn + bn0];

    for (int k0 = 0; k0 < INF; k0 += 32) {
        __syncthreads();   // previous iteration's frag reads complete
        *(unsigned*)&As[am * LDT + ak]        = pack_bf16(av.x, av.y);
        *(unsigned*)&Bs[(bn0 + 0) * LDT + bk] = pack_bf16(bv0.x, bv1.x);
        *(unsigned*)&Bs[(bn0 + 1) * LDT + bk] = pack_bf16(bv0.y, bv1.y);
        *(unsigned*)&Bs[(bn0 + 2) * LDT + bk] = pack_bf16(bv0.z, bv1.z);
        *(unsigned*)&Bs[(bn0 + 3) * LDT + bk] = pack_bf16(bv0.w, bv1.w);
        __syncthreads();

        const int kn = k0 + 32;
        if (kn < INF) {    // issue next-iteration loads; in flight during MFMA
            av  = *(const float2*)&A[(size_t)(bm + am) * INF + kn + ak];
            bv0 = *(const float4*)&B[(size_t)(kn + bk) * PROJ + bn + bn0];
            bv1 = *(const float4*)&B[(size_t)(kn + bk + 1) * PROJ + bn + bn0];
        }

        const short8 af = *(const short8*)ap;
        const short8 bf = *(const short8*)bp;
        acc = __builtin_amdgcn_mfma_f32_16x16x32_bf16(af, bf, acc, 0, 0, 0);
    }

    // epilogue: C/D layout col=lane&15, row=(lane>>4)*4+r -> write fp16 M
#pragma unroll
    for (int r = 0; r < 4; ++r) {
        M16[(size_t)(bm + q * 4 + r) * PROJ + bn + w * 16 + c] = __float2half(acc[r]);
    }
}

// ---------------------------------------------------------------------------
// Kernel 2: pairwise L1 (packed fp16) + exp + sum over one 64-row j-slice,
// atomic accumulate into out[:, 1024:1088].
// Block = 32 i x 4 o (128 thr); grid (og 16, ig 16, js 8) = 2048 blocks.
// LDS 8 KB/block -> 8 blocks/CU resident, 16 waves/CU.
// ---------------------------------------------------------------------------
__global__ __launch_bounds__(128) void pairwise_h2(const __half* __restrict__ M16,
                                                   float* __restrict__ out) {
    __shared__ __half Mj[64 * 64];

    const int t  = threadIdx.x;
    const int o  = t & 3;
    const int il = t >> 2;
    const int og = blockIdx.x;
    const int ig = blockIdx.y;
    const int j0 = blockIdx.z * 64;
    const int i  = ig * 32 + il;

    // my i-row fragment: 16 halves = 32 B
    const uint4* mp = (const uint4*)&M16[(size_t)i * PROJ + og * 64 + o * 16];
    const uint4 a0 = mp[0], a1 = mp[1];

    // stage 64 j-rows x 64 halves (8 KB): 128 thr x 4 x 16 B
#pragma unroll
    for (int cc = 0; cc < 4; ++cc) {
        const int idx = (cc * 128 + t) * 8;  // half index
        const int jl  = idx >> 6;
        const int col = idx & 63;
        *(uint4*)&Mj[jl * 64 + col] =
            *(const uint4*)&M16[(size_t)(j0 + jl) * PROJ + og * 64 + col];
    }
    __syncthreads();

    float sum0 = 0.f, sum1 = 0.f;
#pragma unroll 4
    for (int jl = 0; jl < 64; ++jl) {
        const uint4 b0 = *(const uint4*)&Mj[jl * 64 + o * 16];
        const uint4 b1 = *(const uint4*)&Mj[jl * 64 + o * 16 + 8];
        __half2 s0 = __hadd2(__habs2(__hsub2(as_h2(a0.x), as_h2(b0.x))),
                             __habs2(__hsub2(as_h2(a0.y), as_h2(b0.y))));
        __half2 s1 = __hadd2(__habs2(__hsub2(as_h2(a0.z), as_h2(b0.z))),
                             __habs2(__hsub2(as_h2(a0.w), as_h2(b0.w))));
        __half2 s2 = __hadd2(__habs2(__hsub2(as_h2(a1.x), as_h2(b1.x))),
                             __habs2(__hsub2(as_h2(a1.y), as_h2(b1.y))));
        __half2 s3 = __hadd2(__habs2(__hsub2(as_h2(a1.z), as_h2(b1.z))),
                             __habs2(__hsub2(as_h2(a1.w), as_h2(b1.w))));
        const __half2 s = __hadd2(__hadd2(s0, s1), __hadd2(s2, s3));
        const float norm = __low2float(s) + __high2float(s);
        if (jl & 1) sum1 += __expf(-norm);
        else        sum0 += __expf(-norm);
    }

    __hip_atomic_fetch_add(&out[(size_t)i * OROW + INF + og * 4 + o],
                           sum0 + sum1, __ATOMIC_RELAXED,
                           __HIP_MEMORY_SCOPE_AGENT);
}

extern "C" void kernel_launch(void* const* d_in, const int* in_sizes, int n_in,
                              void* d_out, int out_size, void* d_ws, size_t ws_size,
                              hipStream_t stream) {
    const float* x = (const float*)d_in[0];   // [512,1024] fp32
    const float* T = (const float*)d_in[1];   // [1024,1024] fp32
    float* out  = (float*)d_out;              // [512,1088] fp32
    __half* M16 = (__half*)d_ws;              // [512,1024] fp16 scratch (1 MB)

    gemm_fused<<<dim3(PROJ / 64, NB / 16), 256, 0, stream>>>(x, T, out, M16);
    pairwise_h2<<<dim3(OUTF / 4, NB / 32, NB / 64), 128, 0, stream>>>(M16, out);
}